// Round 1
// 534.178 us; speedup vs baseline: 1.0022x; 1.0022x over previous
//
#include <hip/hip_runtime.h>
#include <hip/hip_bf16.h>
#include <stdint.h>

// Problem constants
#define NB 32
#define NS 8
#define NT 512
#define NC 128
#define NH 128

typedef __bf16 bf16_t;
typedef bf16_t bf16x8 __attribute__((ext_vector_type(8)));
typedef bf16_t bf16x4 __attribute__((ext_vector_type(4)));
typedef float  f32x4  __attribute__((ext_vector_type(4)));

// ---------------------------------------------------------------------------
// k_split: fp32 -> (hi, lo) bf16 pair, elementwise, float4-vectorized.
// hi = rne_bf16(x); lo = rne_bf16(x - (float)hi). hi+lo carries ~16 mantissa bits.
// ---------------------------------------------------------------------------
__global__ __launch_bounds__(256) void k_split(const float* __restrict__ in,
                                               bf16_t* __restrict__ hi,
                                               bf16_t* __restrict__ lo, int n4) {
  int i = blockIdx.x * 256 + threadIdx.x;
  if (i >= n4) return;
  f32x4 x = ((const f32x4*)in)[i];
  bf16x4 h, l;
#pragma unroll
  for (int j = 0; j < 4; j++) {
    bf16_t hb = (bf16_t)x[j];
    h[j] = hb;
    l[j] = (bf16_t)(x[j] - (float)hb);
  }
  ((bf16x4*)hi)[i] = h;
  ((bf16x4*)lo)[i] = l;
}

// ---------------------------------------------------------------------------
// k_prep_w: transpose + split W[c][h] -> Wt{h,l}[mat][h][c]  (rows contiguous
// in c so MFMA B-fragments are 16B contiguous loads).
// ---------------------------------------------------------------------------
__global__ void k_prep_w(const float* __restrict__ Wq, const float* __restrict__ Wk,
                         const float* __restrict__ Wv, bf16_t* __restrict__ Wth,
                         bf16_t* __restrict__ Wtl) {
  int w = blockIdx.x >> 7;      // matrix 0..2
  int h = blockIdx.x & 127;     // output column
  int c = threadIdx.x;          // input row
  const float* W = (w == 0) ? Wq : (w == 1) ? Wk : Wv;
  float x = W[c * NH + h];
  bf16_t hb = (bf16_t)x;
  int o = (w * 128 + h) * 128 + c;
  Wth[o] = hb;
  Wtl[o] = (bf16_t)(x - (float)hb);
}

// ---------------------------------------------------------------------------
// k_qkv: [B*T,128] x [128,128] NT-MFMA with hi/lo split (fp32-accurate).
// blockIdx.y selects matrix: 0->q, 1->k (written directly as hi/lo bf16 pairs
// for k_scores — no fp32 round-trip), 2->v (bf16, transposed to vt[b][h][u]
// for the PV stage's B-fragments).
// ---------------------------------------------------------------------------
__global__ __launch_bounds__(256) void k_qkv(const bf16_t* __restrict__ xh,
                                             const bf16_t* __restrict__ xl,
                                             const bf16_t* __restrict__ Wth,
                                             const bf16_t* __restrict__ Wtl,
                                             bf16_t* __restrict__ qh,
                                             bf16_t* __restrict__ ql,
                                             bf16_t* __restrict__ kh,
                                             bf16_t* __restrict__ kl,
                                             bf16_t* __restrict__ vt) {
  int mat = blockIdx.y;
  int t0 = blockIdx.x * 64;           // global row over B*T
  int lane = threadIdx.x & 63;
  int wave = threadIdx.x >> 6;
  int l15 = lane & 15;
  int kq = (lane >> 4) * 8;           // quad*8: k offset within 32-wide K-step
  int row = t0 + wave * 16 + l15;
  const bf16_t* Wh = Wth + mat * NC * NH;
  const bf16_t* Wl = Wtl + mat * NC * NH;

  f32x4 zero = {0.f, 0.f, 0.f, 0.f};
  f32x4 acc[8];
#pragma unroll
  for (int i = 0; i < 8; i++) acc[i] = zero;

#pragma unroll
  for (int k0 = 0; k0 < NC; k0 += 32) {
    bf16x8 ah = *(const bf16x8*)(xh + (size_t)row * NC + k0 + kq);
    bf16x8 al = *(const bf16x8*)(xl + (size_t)row * NC + k0 + kq);
#pragma unroll
    for (int nt = 0; nt < 8; nt++) {
      bf16x8 bh = *(const bf16x8*)(Wh + (nt * 16 + l15) * NC + k0 + kq);
      bf16x8 bl = *(const bf16x8*)(Wl + (nt * 16 + l15) * NC + k0 + kq);
      acc[nt] = __builtin_amdgcn_mfma_f32_16x16x32_bf16(ah, bh, acc[nt], 0, 0, 0);
      acc[nt] = __builtin_amdgcn_mfma_f32_16x16x32_bf16(ah, bl, acc[nt], 0, 0, 0);
      acc[nt] = __builtin_amdgcn_mfma_f32_16x16x32_bf16(al, bh, acc[nt], 0, 0, 0);
    }
  }

  int trow = t0 + wave * 16 + (lane >> 4) * 4;  // D-layout: row = quad*4 + reg
  if (mat < 2) {
    bf16_t* dh = (mat == 0) ? qh : kh;
    bf16_t* dl = (mat == 0) ? ql : kl;
#pragma unroll
    for (int nt = 0; nt < 8; nt++) {
      int h = nt * 16 + l15;
#pragma unroll
      for (int r = 0; r < 4; r++) {
        float v = acc[nt][r];
        bf16_t hb = (bf16_t)v;
        dh[(size_t)(trow + r) * NH + h] = hb;
        dl[(size_t)(trow + r) * NH + h] = (bf16_t)(v - (float)hb);
      }
    }
  } else {
    int b = trow >> 9;
    int tl = trow & 511;
#pragma unroll
    for (int nt = 0; nt < 8; nt++) {
      int h = nt * 16 + l15;
      bf16x4 pk;
#pragma unroll
      for (int r = 0; r < 4; r++) pk[r] = (bf16_t)acc[nt][r];
      *(bf16x4*)(vt + ((size_t)b * NH + h) * NT + tl) = pk;  // 8B store, 4 consecutive u
    }
  }
}

// ---------------------------------------------------------------------------
// k_scores: wei[b][t][u] = scale * q[b,t,:]·k[b,u,:]  (NT-MFMA, hi/lo split).
// Block tile 64x64; 4 waves stacked along t (B-fragments shared via L1).
// ---------------------------------------------------------------------------
__global__ __launch_bounds__(256) void k_scores(const bf16_t* __restrict__ qh,
                                                const bf16_t* __restrict__ ql,
                                                const bf16_t* __restrict__ kh,
                                                const bf16_t* __restrict__ kl,
                                                float* __restrict__ wei) {
  int b = blockIdx.y;
  int mt = blockIdx.x >> 3;
  int ut = blockIdx.x & 7;
  int lane = threadIdx.x & 63;
  int wave = threadIdx.x >> 6;
  int l15 = lane & 15;
  int kq = (lane >> 4) * 8;
  int m0 = mt * 64 + wave * 16;
  int u0 = ut * 64;
  const float scale = 0.08838834764831845f;  // 128^-0.5

  f32x4 zero = {0.f, 0.f, 0.f, 0.f};
  f32x4 acc[4];
#pragma unroll
  for (int i = 0; i < 4; i++) acc[i] = zero;

  size_t qbase = ((size_t)b * NT + m0 + l15) * NH;
  size_t kbase = ((size_t)b * NT + u0 + l15) * NH;

#pragma unroll
  for (int k0 = 0; k0 < NH; k0 += 32) {
    bf16x8 ah = *(const bf16x8*)(qh + qbase + k0 + kq);
    bf16x8 al = *(const bf16x8*)(ql + qbase + k0 + kq);
#pragma unroll
    for (int nt = 0; nt < 4; nt++) {
      bf16x8 bh = *(const bf16x8*)(kh + kbase + (size_t)nt * 16 * NH + k0 + kq);
      bf16x8 bl = *(const bf16x8*)(kl + kbase + (size_t)nt * 16 * NH + k0 + kq);
      acc[nt] = __builtin_amdgcn_mfma_f32_16x16x32_bf16(ah, bh, acc[nt], 0, 0, 0);
      acc[nt] = __builtin_amdgcn_mfma_f32_16x16x32_bf16(ah, bl, acc[nt], 0, 0, 0);
      acc[nt] = __builtin_amdgcn_mfma_f32_16x16x32_bf16(al, bh, acc[nt], 0, 0, 0);
    }
  }

  int t = m0 + (lane >> 4) * 4;
#pragma unroll
  for (int nt = 0; nt < 4; nt++) {
    int u = u0 + nt * 16 + l15;
#pragma unroll
    for (int r = 0; r < 4; r++)
      wei[((size_t)b * NT + t + r) * NT + u] = acc[nt][r] * scale;
  }
}

// ---------------------------------------------------------------------------
// k_attn v2: per (b, 16-row t-tile) block; loops s INSIDE the block.
//  - wei tile (16 rows x 512) cached in registers ONCE (kills the 8x re-read
//    that previously went through L3 with full latency exposure).
//  - adj for s+1 prefetched into registers during PV of s (HBM latency hides
//    under MFMA + epilogue work).
//  - p double-buffered in LDS (2 x 16 x PLD bf16 = 33 KB) -> ONE barrier per s.
//  - __launch_bounds__(256,4): 128-VGPR budget so the prefetch regs exist.
//  Grid = (NT/16, NB) = 1024 blocks = exactly 4/CU, zero tail.
//  Numerics identical to v1 (same __expf path, bf16 P, ones-MFMA denom).
// ---------------------------------------------------------------------------
#define PLD 520  // 512 + 8 bf16 pad

__global__ __launch_bounds__(256, 4) void k_attn(const float* __restrict__ wei,
                                                 const float* __restrict__ adj,
                                                 const bf16_t* __restrict__ vt,
                                                 float* __restrict__ out) {
  __shared__ bf16_t p[2][16 * PLD];
  int t0 = blockIdx.x * 16;
  int b = blockIdx.y;
  int lane = threadIdx.x & 63;
  int wave = threadIdx.x >> 6;
  int l15 = lane & 15;
  int kq = (lane >> 4) * 8;
  int h0 = wave * 32;  // each wave owns a 32-wide h slab in PV

  // ---- cache wei rows (wave*4 + rr) in registers, read once per block ----
  f32x4 wf0[4], wf1[4];
#pragma unroll
  for (int rr = 0; rr < 4; rr++) {
    const float* wrow = wei + ((size_t)b * NT + t0 + wave * 4 + rr) * NT;
    wf0[rr] = ((const f32x4*)wrow)[lane];        // u = lane*4
    wf1[rr] = ((const f32x4*)wrow)[64 + lane];   // u = 256 + lane*4
  }

  const bf16_t* vb = vt + (size_t)b * NH * NT;
  bf16x8 ones;
#pragma unroll
  for (int j = 0; j < 8; j++) ones[j] = (bf16_t)1.0f;

  // ---- prefetch adj for s = 0 ----
  f32x4 a0[4], a1[4];
#pragma unroll
  for (int rr = 0; rr < 4; rr++) {
    const float* arow = adj + ((size_t)b * NS * NT + t0 + wave * 4 + rr) * NT;
    a0[rr] = ((const f32x4*)arow)[lane];
    a1[rr] = ((const f32x4*)arow)[64 + lane];
  }

  for (int s = 0; s < NS; s++) {
    // ---- Pass A: p = exp(wei*adj), bf16, rows wave*4..+3, buffer s&1 ----
    bf16_t* pb = &p[s & 1][0];
#pragma unroll
    for (int rr = 0; rr < 4; rr++) {
      int r = wave * 4 + rr;
      bf16x4 e0, e1;
#pragma unroll
      for (int j = 0; j < 4; j++) e0[j] = (bf16_t)__expf(wf0[rr][j] * a0[rr][j]);
#pragma unroll
      for (int j = 0; j < 4; j++) e1[j] = (bf16_t)__expf(wf1[rr][j] * a1[rr][j]);
      *(bf16x4*)&pb[r * PLD + lane * 4] = e0;
      *(bf16x4*)&pb[r * PLD + 256 + lane * 4] = e1;
    }
    __syncthreads();  // p[s&1] complete; prior PV on p[s&1] finished >=1 barrier ago

    // ---- prefetch adj for s+1 (regs free after exp); hides under PV ----
    if (s + 1 < NS) {
#pragma unroll
      for (int rr = 0; rr < 4; rr++) {
        const float* arow =
            adj + (((size_t)b * NS + s + 1) * NT + t0 + wave * 4 + rr) * NT;
        a0[rr] = ((const f32x4*)arow)[lane];
        a1[rr] = ((const f32x4*)arow)[64 + lane];
      }
    }

    // ---- Pass B: out[t0..t0+16, h0..h0+32] = (P @ V) / (P @ 1) ----
    f32x4 zero = {0.f, 0.f, 0.f, 0.f};
    f32x4 acc[2] = {zero, zero};
    f32x4 accl = zero;
#pragma unroll 4
    for (int k0 = 0; k0 < NT; k0 += 32) {
      bf16x8 afr = *(const bf16x8*)&pb[l15 * PLD + k0 + kq];
      accl = __builtin_amdgcn_mfma_f32_16x16x32_bf16(afr, ones, accl, 0, 0, 0);
#pragma unroll
      for (int nt = 0; nt < 2; nt++) {
        bf16x8 bfr =
            *(const bf16x8*)(vb + (size_t)(h0 + nt * 16 + l15) * NT + k0 + kq);
        acc[nt] = __builtin_amdgcn_mfma_f32_16x16x32_bf16(afr, bfr, acc[nt], 0, 0, 0);
      }
    }

    // ---- epilogue: divide by row sums, store ----
    int tl = (lane >> 4) * 4;
    float linv[4];
#pragma unroll
    for (int r = 0; r < 4; r++) linv[r] = 1.0f / accl[r];
    float* obase = out + (((size_t)b * NS + s) * NT + t0) * NH;
#pragma unroll
    for (int nt = 0; nt < 2; nt++) {
      int h = h0 + nt * 16 + l15;
#pragma unroll
      for (int r = 0; r < 4; r++)
        obase[(size_t)(tl + r) * NH + h] = acc[nt][r] * linv[r];
    }
    // no trailing barrier: next iteration writes the OTHER p buffer, and the
    // next __syncthreads() orders reuse of this one.
  }
}

// ---------------------------------------------------------------------------
extern "C" void kernel_launch(void* const* d_in, const int* in_sizes, int n_in,
                              void* d_out, int out_size, void* d_ws, size_t ws_size,
                              hipStream_t stream) {
  const float* x = (const float*)d_in[0];
  const float* adj = (const float*)d_in[1];
  const float* Wq = (const float*)d_in[2];
  const float* Wk = (const float*)d_in[3];
  const float* Wv = (const float*)d_in[4];
  float* out = (float*)d_out;

  const size_t BTC = (size_t)NB * NT * NC;  // 2,097,152 elements

  // Workspace carve-up (all 16B-aligned chunks); total ~62 MB
  char* base = (char*)d_ws;
  bf16_t* xh = (bf16_t*)base;  base += BTC * 2;
  bf16_t* xl = (bf16_t*)base;  base += BTC * 2;
  bf16_t* Wth = (bf16_t*)base; base += (size_t)3 * NC * NH * 2;
  bf16_t* Wtl = (bf16_t*)base; base += (size_t)3 * NC * NH * 2;
  bf16_t* qh = (bf16_t*)base;  base += BTC * 2;
  bf16_t* ql = (bf16_t*)base;  base += BTC * 2;
  bf16_t* kh = (bf16_t*)base;  base += BTC * 2;
  bf16_t* kl = (bf16_t*)base;  base += BTC * 2;
  bf16_t* vt = (bf16_t*)base;  base += BTC * 2;
  float* wei = (float*)base;   base += (size_t)NB * NT * NT * 4;
  (void)in_sizes; (void)n_in; (void)out_size; (void)ws_size;

  // 1. split x into hi/lo bf16
  k_split<<<(int)(BTC / 4 / 256), 256, 0, stream>>>(x, xh, xl, (int)(BTC / 4));
  // 2. transpose+split W
  k_prep_w<<<384, 128, 0, stream>>>(Wq, Wk, Wv, Wth, Wtl);
  // 3. q,k -> hi/lo bf16 directly; v -> vt bf16 transposed
  k_qkv<<<dim3((int)(NB * NT / 64), 3), 256, 0, stream>>>(xh, xl, Wth, Wtl,
                                                          qh, ql, kh, kl, vt);
  // 4. scores
  k_scores<<<dim3(64, NB), 256, 0, stream>>>(qh, ql, kh, kl, wei);
  // 5. softmax + PV, s-loop inside block
  k_attn<<<dim3(NT / 16, NB), 256, 0, stream>>>(wei, adj, vt, out);
}